// Round 6
// baseline (313.009 us; speedup 1.0000x reference)
//
#include <hip/hip_runtime.h>

// Problem constants
#define NN 100000   // nodes
#define FD 256      // feature dim
#define ED 128      // embedding dim
#define BB 8192     // batch
#define DD 32       // neighbors per relation
#define KSEL 16     // top-k

typedef unsigned short ushort_t;

static __device__ __forceinline__ float b2f(ushort_t u) {
    union { float f; unsigned int i; } v; v.i = ((unsigned int)u) << 16; return v.f;
}
static __device__ __forceinline__ ushort_t f2b(float f) {
    union { float f; unsigned int i; } v; v.f = f;
    unsigned int x = v.i;
    x += 0x7fffu + ((x >> 16) & 1u);   // round-to-nearest-even
    return (ushort_t)(x >> 16);
}
static __device__ __forceinline__ int clampid(int v) {
    return v < 0 ? 0 : (v >= NN ? NN - 1 : v);   // defensive: no wild addresses
}

// ===========================================================================
// FAST PATH (3-kernel pipeline, needs ws >= 7,091,456 B)
// ===========================================================================

// K1: s0a[n], s1a[n] = features[n] @ wc + bc. One wave per row.
__global__ __launch_bounds__(256) void k_scores(
    const float* __restrict__ feats, const float* __restrict__ wc,
    const float* __restrict__ bc,
    float* __restrict__ s0a, float* __restrict__ s1a)
{
    const int lane = threadIdx.x & 63;
    const int wave = blockIdx.x * 4 + (threadIdx.x >> 6);
    const int nwaves = gridDim.x * 4;

    const float4 wa  = *(const float4*)(wc + lane * 8);
    const float4 wb_ = *(const float4*)(wc + lane * 8 + 4);
    const float w00 = wa.x, w01 = wa.z, w02 = wb_.x, w03 = wb_.z;
    const float w10 = wa.y, w11 = wa.w, w12 = wb_.y, w13 = wb_.w;
    const float bc0 = bc[0], bc1 = bc[1];

    for (int row = wave; row < NN; row += nwaves) {
        const float4 f4 = *(const float4*)(feats + (size_t)row * FD + lane * 4);
        float s0 = f4.x * w00 + f4.y * w01 + f4.z * w02 + f4.w * w03;
        float s1 = f4.x * w10 + f4.y * w11 + f4.z * w12 + f4.w * w13;
        #pragma unroll
        for (int o = 32; o; o >>= 1) {
            s0 += __shfl_xor(s0, o);
            s1 += __shfl_xor(s1, o);
        }
        if (lane == 0) {
            s0a[row] = s0 + bc0;
            s1a[row] = s1 + bc1;
        }
    }
}

// K2: per (32-row batch tile, relation): top-16 select -> gather+mean
// -> GEMM 32x256 @ 256x128 -> relu -> r_buf (bf16). Grid (BB/32, 3).
// LDS 34.9 KB -> 4 blocks/CU (occupancy diet vs R5's 51.7 KB / 3 blocks).
__global__ __launch_bounds__(256, 4) void k_rel(
    const float* __restrict__ feats, const float* __restrict__ s1a,
    const int* __restrict__ nodes,
    const int* __restrict__ n1, const int* __restrict__ n2,
    const int* __restrict__ n3,
    const float* __restrict__ w1, const float* __restrict__ w2,
    const float* __restrict__ w3,
    ushort_t* __restrict__ r_buf)
{
    const int r  = blockIdx.y;
    const int b0 = blockIdx.x * 32;
    const int* nr = (r == 0) ? n1 : (r == 1) ? n2 : n3;
    const float* W = (r == 0) ? w1 : (r == 1) ? w2 : w3;

    __shared__ __align__(16) ushort_t Am[32 * FD];   // mean tile bf16, 16 KB
    __shared__ __align__(16) float Bsm[32 * ED];     // W k-chunk, 16 KB
    __shared__ int   sl[32 * KSEL];                  // 2 KB
    __shared__ float cs1[32];
    int* nb = (int*)Bsm;   // alias: nb dead before Bsm first written

    const int t    = threadIdx.x;
    const int wv   = t >> 6;
    const int lane = t & 63;

    if (t < 32) cs1[t] = s1a[clampid(nodes[b0 + t])];
    #pragma unroll
    for (int jj = 0; jj < 4; ++jj) {
        const int idx = t + 256 * jj;
        nb[idx] = clampid(nr[(size_t)b0 * DD + idx]);
    }
    __syncthreads();

    // prefill sl with valid ids (rank collisions can't leave garbage)
    #pragma unroll
    for (int jj = 0; jj < 2; ++jj) {
        const int idx = t + 256 * jj;          // 0..511
        sl[idx] = nb[(idx >> 4) * DD + (idx & 15)];
    }
    __syncthreads();

    // top-16 by rank (exact jax.lax.top_k stable tie-break)
    {
        const int g = t >> 5;
        const int j = t & 31;
        #pragma unroll
        for (int pass = 0; pass < 4; ++pass) {
            const int row = pass * 8 + g;
            const float d = fabsf(s1a[nb[row * DD + j]] - cs1[row]);
            int rank = 0;
            #pragma unroll
            for (int k = 0; k < 32; ++k) {
                const float dk = __shfl(d, k, 32);
                rank += (dk < d) || (dk == d && k < j);
            }
            if (rank < KSEL) sl[row * KSEL + rank] = nb[row * DD + j];
        }
    }
    __syncthreads();

    // gather + mean, two rows interleaved per iteration (2x loads in flight)
    for (int rr = wv * 8; rr < wv * 8 + 8; rr += 2) {
        float a0 = 0.f, a1 = 0.f, a2 = 0.f, a3 = 0.f;
        float b0v = 0.f, b1v = 0.f, b2v = 0.f, b3v = 0.f;
        #pragma unroll
        for (int k = 0; k < KSEL; ++k) {
            const int s0i = sl[rr * KSEL + k];
            const int s1i = sl[(rr + 1) * KSEL + k];
            const float4 v0 = *(const float4*)(feats + (size_t)s0i * FD + lane * 4);
            const float4 v1 = *(const float4*)(feats + (size_t)s1i * FD + lane * 4);
            a0 += v0.x; a1 += v0.y; a2 += v0.z; a3 += v0.w;
            b0v += v1.x; b1v += v1.y; b2v += v1.z; b3v += v1.w;
        }
        ushort4 oa, ob;
        oa.x = f2b(a0 * 0.0625f);  oa.y = f2b(a1 * 0.0625f);
        oa.z = f2b(a2 * 0.0625f);  oa.w = f2b(a3 * 0.0625f);
        ob.x = f2b(b0v * 0.0625f); ob.y = f2b(b1v * 0.0625f);
        ob.z = f2b(b2v * 0.0625f); ob.w = f2b(b3v * 0.0625f);
        *(ushort4*)(Am + rr * FD + lane * 4)       = oa;
        *(ushort4*)(Am + (rr + 1) * FD + lane * 4) = ob;
    }
    __syncthreads();

    // GEMM 32x256 @ 256x128, BK=32, 4x4 micro-tile, A from bf16 LDS
    const int bt = (t >> 5) * 4;
    const int et = (t & 31) * 4;
    float acc[4][4] = {};

    for (int k0 = 0; k0 < FD; k0 += 32) {
        #pragma unroll
        for (int jj = 0; jj < 4; ++jj) {
            const int c = t + 256 * jj;
            const int row = c >> 5, col4 = (c & 31) * 4;
            *(float4*)(Bsm + row * ED + col4) =
                *(const float4*)(W + (size_t)(k0 + row) * ED + col4);
        }
        __syncthreads();
        #pragma unroll
        for (int kk = 0; kk < 32; kk += 4) {
            ushort4 av[4];
            #pragma unroll
            for (int i = 0; i < 4; ++i)
                av[i] = *(const ushort4*)(Am + (bt + i) * FD + k0 + kk);
            #pragma unroll
            for (int q = 0; q < 4; ++q) {
                const float4 bv = *(const float4*)(Bsm + (kk + q) * ED + et);
                const float a0 = b2f(q == 0 ? av[0].x : q == 1 ? av[0].y : q == 2 ? av[0].z : av[0].w);
                const float a1 = b2f(q == 0 ? av[1].x : q == 1 ? av[1].y : q == 2 ? av[1].z : av[1].w);
                const float a2 = b2f(q == 0 ? av[2].x : q == 1 ? av[2].y : q == 2 ? av[2].z : av[2].w);
                const float a3 = b2f(q == 0 ? av[3].x : q == 1 ? av[3].y : q == 2 ? av[3].z : av[3].w);
                acc[0][0] += a0 * bv.x; acc[0][1] += a0 * bv.y;
                acc[0][2] += a0 * bv.z; acc[0][3] += a0 * bv.w;
                acc[1][0] += a1 * bv.x; acc[1][1] += a1 * bv.y;
                acc[1][2] += a1 * bv.z; acc[1][3] += a1 * bv.w;
                acc[2][0] += a2 * bv.x; acc[2][1] += a2 * bv.y;
                acc[2][2] += a2 * bv.z; acc[2][3] += a2 * bv.w;
                acc[3][0] += a3 * bv.x; acc[3][1] += a3 * bv.y;
                acc[3][2] += a3 * bv.z; acc[3][3] += a3 * bv.w;
            }
        }
        __syncthreads();
    }

    #pragma unroll
    for (int i = 0; i < 4; ++i) {
        ushort4 o;
        const float v0 = acc[i][0], v1 = acc[i][1], v2 = acc[i][2], v3 = acc[i][3];
        o.x = f2b(v0 > 0.f ? v0 : 0.f);
        o.y = f2b(v1 > 0.f ? v1 : 0.f);
        o.z = f2b(v2 > 0.f ? v2 : 0.f);
        o.w = f2b(v3 > 0.f ? v3 : 0.f);
        *(ushort4*)(r_buf + (size_t)(r * BB + b0 + bt + i) * ED + et) = o;
    }
}

// K3: final GEMM 32x640 @ 640x128, A = [feats[nodes] | r_buf], N-split 2.
__global__ __launch_bounds__(256) void k_fin(
    const float* __restrict__ feats, const int* __restrict__ nodes,
    const ushort_t* __restrict__ r_buf, const float* __restrict__ weight,
    const float* __restrict__ s0a, const float* __restrict__ s1a,
    float* __restrict__ out)
{
    const int b0 = blockIdx.x * 32;
    const int e0 = blockIdx.y * 64;
    const int t = threadIdx.x;

    __shared__ __align__(16) unsigned char mem[12800];
    float* Asf = (float*)mem;              // [32*36]  4608 B
    float* Bs2 = (float*)(mem + 4608);     // [32*64]  8192 B
    float* Cs  = (float*)mem;              // [64*36]  epilogue alias
    __shared__ int nid[32];

    if (t < 32) nid[t] = clampid(nodes[b0 + t]);
    __syncthreads();

    if (blockIdx.y == 0 && t < 64) {       // center scores -> out tail
        const int i = t >> 1;
        out[(size_t)ED * BB + (size_t)(b0 + i) * 2 + (t & 1)] =
            (t & 1) ? s1a[nid[i]] : s0a[nid[i]];
    }

    const int arow = t >> 3;
    const int acol = (t & 7) * 4;
    const int bt3 = (t >> 4) * 2;
    const int et3 = (t & 15) * 4;
    float acc[2][4] = {};

    for (int k0 = 0; k0 < FD + 3 * ED; k0 += 32) {
        if (k0 < FD) {
            const float4 v = *(const float4*)(feats + (size_t)nid[arow] * FD + k0 + acol);
            Asf[arow * 36 + acol + 0] = v.x;
            Asf[arow * 36 + acol + 1] = v.y;
            Asf[arow * 36 + acol + 2] = v.z;
            Asf[arow * 36 + acol + 3] = v.w;
        } else {
            const int kr = k0 - FD;
            const ushort4 v = *(const ushort4*)(r_buf +
                (size_t)((kr >> 7) * BB + b0 + arow) * ED + (kr & 127) + acol);
            Asf[arow * 36 + acol + 0] = b2f(v.x);
            Asf[arow * 36 + acol + 1] = b2f(v.y);
            Asf[arow * 36 + acol + 2] = b2f(v.z);
            Asf[arow * 36 + acol + 3] = b2f(v.w);
        }
        #pragma unroll
        for (int jj = 0; jj < 2; ++jj) {
            const int c = t + 256 * jj;        // 0..511
            const int row = c >> 4, col4 = (c & 15) * 4;
            *(float4*)(Bs2 + row * 64 + col4) =
                *(const float4*)(weight + (size_t)(k0 + row) * ED + e0 + col4);
        }
        __syncthreads();
        #pragma unroll
        for (int kk = 0; kk < 32; ++kk) {
            const float a0 = Asf[(bt3 + 0) * 36 + kk];
            const float a1 = Asf[(bt3 + 1) * 36 + kk];
            const float4 bv = *(const float4*)(Bs2 + kk * 64 + et3);
            acc[0][0] += a0 * bv.x; acc[0][1] += a0 * bv.y;
            acc[0][2] += a0 * bv.z; acc[0][3] += a0 * bv.w;
            acc[1][0] += a1 * bv.x; acc[1][1] += a1 * bv.y;
            acc[1][2] += a1 * bv.z; acc[1][3] += a1 * bv.w;
        }
        __syncthreads();
    }

    #pragma unroll
    for (int i = 0; i < 2; ++i)
        #pragma unroll
        for (int j = 0; j < 4; ++j) {
            const float v = acc[i][j];
            Cs[(et3 + j) * 36 + bt3 + i] = v > 0.f ? v : 0.f;
        }
    __syncthreads();
    #pragma unroll
    for (int jj = 0; jj < 2; ++jj) {
        const int c = t + 256 * jj;            // 512 slots: 64 rows x 8 float4
        const int er = c >> 3;
        const int off = (c & 7) * 4;
        *(float4*)(out + (size_t)(e0 + er) * BB + b0 + off) =
            *(const float4*)(Cs + er * 36 + off);
    }
}

// ===========================================================================
// FALLBACK (validated R4 single kernel, zero workspace)
// ===========================================================================
__global__ __launch_bounds__(256) void k_fused(
    const float* __restrict__ feats, const int* __restrict__ nodes,
    const int* __restrict__ n1, const int* __restrict__ n2,
    const int* __restrict__ n3,
    const float* __restrict__ wc, const float* __restrict__ bc,
    const float* __restrict__ w1, const float* __restrict__ w2,
    const float* __restrict__ w3,
    const float* __restrict__ weight, float* __restrict__ out)
{
    __shared__ __align__(16) unsigned char usm[32768];
    __shared__ int      sl[32 * KSEL];
    __shared__ __align__(16) ushort_t Rt[3 * 32 * ED];
    __shared__ int      nid[32];
    __shared__ float    cs1[32];

    int*      nb  = (int*)usm;
    float*    ns1 = (float*)(usm + 4096);
    ushort_t* Am  = (ushort_t*)usm;
    float*    Bsm = (float*)(usm + 16384);
    float*    Asf = (float*)usm;
    float*    Cs  = (float*)usm;

    const int b0   = blockIdx.x * 32;
    const int t    = threadIdx.x;
    const int wv   = t >> 6;
    const int lane = t & 63;

    const float4 wa  = *(const float4*)(wc + lane * 8);
    const float4 wb_ = *(const float4*)(wc + lane * 8 + 4);
    const float w00 = wa.x, w01 = wa.z, w02 = wb_.x, w03 = wb_.z;
    const float w10 = wa.y, w11 = wa.w, w12 = wb_.y, w13 = wb_.w;
    const float bc0 = bc[0], bc1 = bc[1];

    if (t < 32) nid[t] = clampid(nodes[b0 + t]);
    __syncthreads();

    for (int q = 0; q < 8; ++q) {
        const int i = wv * 8 + q;
        const int node = nid[i];
        const float4 f4 = *(const float4*)(feats + (size_t)node * FD + lane * 4);
        float s0 = f4.x * w00 + f4.y * w01 + f4.z * w02 + f4.w * w03;
        float s1 = f4.x * w10 + f4.y * w11 + f4.z * w12 + f4.w * w13;
        #pragma unroll
        for (int o = 32; o; o >>= 1) {
            s0 += __shfl_xor(s0, o);
            s1 += __shfl_xor(s1, o);
        }
        if (lane == 0) {
            cs1[i] = s1 + bc1;
            out[(size_t)ED * BB + (size_t)(b0 + i) * 2]     = s0 + bc0;
            out[(size_t)ED * BB + (size_t)(b0 + i) * 2 + 1] = s1 + bc1;
        }
    }
    __syncthreads();

    const int bt = (t >> 5) * 4;
    const int et = (t & 31) * 4;

    for (int r = 0; r < 3; ++r) {
        const int* nr = (r == 0) ? n1 : (r == 1) ? n2 : n3;
        const float* W = (r == 0) ? w1 : (r == 1) ? w2 : w3;

        #pragma unroll
        for (int jj = 0; jj < 4; ++jj) {
            const int idx = t + 256 * jj;
            nb[idx] = clampid(nr[(size_t)b0 * DD + idx]);
        }
        __syncthreads();

        #pragma unroll
        for (int jj = 0; jj < 2; ++jj) {
            const int idx = t + 256 * jj;
            sl[idx] = nb[(idx >> 4) * DD + (idx & 15)];
        }

        for (int p = wv; p < 32 * DD; p += 4) {
            const int node = nb[p];
            const float4 f4 = *(const float4*)(feats + (size_t)node * FD + lane * 4);
            float s1 = f4.x * w10 + f4.y * w11 + f4.z * w12 + f4.w * w13;
            #pragma unroll
            for (int o = 32; o; o >>= 1) s1 += __shfl_xor(s1, o);
            if (lane == 0) ns1[p] = s1 + bc1;
        }
        __syncthreads();

        {
            const int g = t >> 5;
            const int j = t & 31;
            #pragma unroll
            for (int pass = 0; pass < 4; ++pass) {
                const int row = pass * 8 + g;
                const float d = fabsf(ns1[row * DD + j] - cs1[row]);
                int rank = 0;
                #pragma unroll
                for (int k = 0; k < 32; ++k) {
                    const float dk = __shfl(d, k, 32);
                    rank += (dk < d) || (dk == d && k < j);
                }
                if (rank < KSEL) sl[row * KSEL + rank] = nb[row * DD + j];
            }
        }
        __syncthreads();

        for (int rr = wv * 8; rr < wv * 8 + 8; ++rr) {
            float a0 = 0.f, a1 = 0.f, a2 = 0.f, a3 = 0.f;
            #pragma unroll
            for (int k = 0; k < KSEL; ++k) {
                const int src = sl[rr * KSEL + k];
                const float4 v = *(const float4*)(feats + (size_t)src * FD + lane * 4);
                a0 += v.x; a1 += v.y; a2 += v.z; a3 += v.w;
            }
            ushort4 o;
            o.x = f2b(a0 * 0.0625f); o.y = f2b(a1 * 0.0625f);
            o.z = f2b(a2 * 0.0625f); o.w = f2b(a3 * 0.0625f);
            *(ushort4*)(Am + rr * FD + lane * 4) = o;
        }
        __syncthreads();

        float acc[4][4] = {};
        for (int k0 = 0; k0 < FD; k0 += 32) {
            #pragma unroll
            for (int jj = 0; jj < 4; ++jj) {
                const int c = t + 256 * jj;
                const int row = c >> 5, col4 = (c & 31) * 4;
                *(float4*)(Bsm + row * ED + col4) =
                    *(const float4*)(W + (size_t)(k0 + row) * ED + col4);
            }
            __syncthreads();
            #pragma unroll
            for (int kk = 0; kk < 32; kk += 4) {
                ushort4 av[4];
                #pragma unroll
                for (int i = 0; i < 4; ++i)
                    av[i] = *(const ushort4*)(Am + (bt + i) * FD + k0 + kk);
                #pragma unroll
                for (int q = 0; q < 4; ++q) {
                    const float4 bv = *(const float4*)(Bsm + (kk + q) * ED + et);
                    const float a0 = b2f(q == 0 ? av[0].x : q == 1 ? av[0].y : q == 2 ? av[0].z : av[0].w);
                    const float a1 = b2f(q == 0 ? av[1].x : q == 1 ? av[1].y : q == 2 ? av[1].z : av[1].w);
                    const float a2 = b2f(q == 0 ? av[2].x : q == 1 ? av[2].y : q == 2 ? av[2].z : av[2].w);
                    const float a3 = b2f(q == 0 ? av[3].x : q == 1 ? av[3].y : q == 2 ? av[3].z : av[3].w);
                    acc[0][0] += a0 * bv.x; acc[0][1] += a0 * bv.y;
                    acc[0][2] += a0 * bv.z; acc[0][3] += a0 * bv.w;
                    acc[1][0] += a1 * bv.x; acc[1][1] += a1 * bv.y;
                    acc[1][2] += a1 * bv.z; acc[1][3] += a1 * bv.w;
                    acc[2][0] += a2 * bv.x; acc[2][1] += a2 * bv.y;
                    acc[2][2] += a2 * bv.z; acc[2][3] += a2 * bv.w;
                    acc[3][0] += a3 * bv.x; acc[3][1] += a3 * bv.y;
                    acc[3][2] += a3 * bv.z; acc[3][3] += a3 * bv.w;
                }
            }
            __syncthreads();
        }

        #pragma unroll
        for (int i = 0; i < 4; ++i) {
            ushort4 o;
            const float v0 = acc[i][0], v1 = acc[i][1], v2 = acc[i][2], v3 = acc[i][3];
            o.x = f2b(v0 > 0.f ? v0 : 0.f);
            o.y = f2b(v1 > 0.f ? v1 : 0.f);
            o.z = f2b(v2 > 0.f ? v2 : 0.f);
            o.w = f2b(v3 > 0.f ? v3 : 0.f);
            *(ushort4*)(Rt + (r * 32 + bt + i) * ED + et) = o;
        }
    }

    const int arow = t >> 3;
    const int acol = (t & 7) * 4;
    float acc[4][4] = {};

    for (int k0 = 0; k0 < FD + 3 * ED; k0 += 32) {
        if (k0 < FD) {
            const float4 v = *(const float4*)(feats + (size_t)nid[arow] * FD + k0 + acol);
            Asf[arow * 36 + acol + 0] = v.x;
            Asf[arow * 36 + acol + 1] = v.y;
            Asf[arow * 36 + acol + 2] = v.z;
            Asf[arow * 36 + acol + 3] = v.w;
        } else {
            const int kr = k0 - FD;
            const ushort4 v = *(const ushort4*)(Rt + ((kr >> 7) * 32 + arow) * ED + (kr & 127) + acol);
            Asf[arow * 36 + acol + 0] = b2f(v.x);
            Asf[arow * 36 + acol + 1] = b2f(v.y);
            Asf[arow * 36 + acol + 2] = b2f(v.z);
            Asf[arow * 36 + acol + 3] = b2f(v.w);
        }
        #pragma unroll
        for (int jj = 0; jj < 4; ++jj) {
            const int c = t + 256 * jj;
            const int row = c >> 5, col4 = (c & 31) * 4;
            *(float4*)(Bsm + row * ED + col4) =
                *(const float4*)(weight + (size_t)(k0 + row) * ED + col4);
        }
        __syncthreads();
        #pragma unroll
        for (int kk = 0; kk < 32; ++kk) {
            const float a0 = Asf[(bt + 0) * 36 + kk];
            const float a1 = Asf[(bt + 1) * 36 + kk];
            const float a2 = Asf[(bt + 2) * 36 + kk];
            const float a3 = Asf[(bt + 3) * 36 + kk];
            const float4 bv = *(const float4*)(Bsm + kk * ED + et);
            acc[0][0] += a0 * bv.x; acc[0][1] += a0 * bv.y;
            acc[0][2] += a0 * bv.z; acc[0][3] += a0 * bv.w;
            acc[1][0] += a1 * bv.x; acc[1][1] += a1 * bv.y;
            acc[1][2] += a1 * bv.z; acc[1][3] += a1 * bv.w;
            acc[2][0] += a2 * bv.x; acc[2][1] += a2 * bv.y;
            acc[2][2] += a2 * bv.z; acc[2][3] += a2 * bv.w;
            acc[3][0] += a3 * bv.x; acc[3][1] += a3 * bv.y;
            acc[3][2] += a3 * bv.z; acc[3][3] += a3 * bv.w;
        }
        __syncthreads();
    }

    #pragma unroll
    for (int i = 0; i < 4; ++i)
        #pragma unroll
        for (int j = 0; j < 4; ++j) {
            const float v = acc[i][j];
            Cs[(et + j) * 36 + bt + i] = v > 0.f ? v : 0.f;
        }
    __syncthreads();
    #pragma unroll
    for (int jj = 0; jj < 4; ++jj) {
        const int c = t + 256 * jj;
        const int er = c >> 3;
        const int off = (c & 7) * 4;
        *(float4*)(out + (size_t)er * BB + b0 + off) = *(const float4*)(Cs + er * 36 + off);
    }
}

// ---------------------------------------------------------------------------
// ws layout (fast path): s0a f32[NN]@0, s1a f32[NN]@400000,
// r_buf bf16[3*BB*ED]@800000. Total 7,091,456 B.
// ---------------------------------------------------------------------------
extern "C" void kernel_launch(void* const* d_in, const int* in_sizes, int n_in,
                              void* d_out, int out_size, void* d_ws, size_t ws_size,
                              hipStream_t stream)
{
    const float* feats  = (const float*)d_in[0];
    const int*   nodes  = (const int*)d_in[1];
    const int*   n1     = (const int*)d_in[2];
    const int*   n2     = (const int*)d_in[3];
    const int*   n3     = (const int*)d_in[4];
    const float* wc     = (const float*)d_in[5];
    const float* bc     = (const float*)d_in[6];
    const float* w1     = (const float*)d_in[7];
    const float* w2     = (const float*)d_in[8];
    const float* w3     = (const float*)d_in[9];
    const float* weight = (const float*)d_in[10];
    float* out = (float*)d_out;

    if (ws_size >= 7091456) {
        char* ws = (char*)d_ws;
        float*    s0a   = (float*)(ws + 0);
        float*    s1a   = (float*)(ws + 400000);
        ushort_t* r_buf = (ushort_t*)(ws + 800000);

        k_scores<<<800, 256, 0, stream>>>(feats, wc, bc, s0a, s1a);
        k_rel<<<dim3(BB / 32, 3), 256, 0, stream>>>(
            feats, s1a, nodes, n1, n2, n3, w1, w2, w3, r_buf);
        k_fin<<<dim3(BB / 32, 2), 256, 0, stream>>>(
            feats, nodes, r_buf, weight, s0a, s1a, out);
    } else {
        k_fused<<<BB / 32, 256, 0, stream>>>(feats, nodes, n1, n2, n3,
                                             wc, bc, w1, w2, w3, weight, out);
    }
}

// Round 7
// 291.020 us; speedup vs baseline: 1.0756x; 1.0756x over previous
//
#include <hip/hip_runtime.h>

// Problem constants
#define NN 100000   // nodes
#define FD 256      // feature dim
#define ED 128      // embedding dim
#define BB 8192     // batch
#define DD 32       // neighbors per relation
#define KSEL 16     // top-k

typedef unsigned short ushort_t;

static __device__ __forceinline__ float b2f(ushort_t u) {
    union { float f; unsigned int i; } v; v.i = ((unsigned int)u) << 16; return v.f;
}
static __device__ __forceinline__ ushort_t f2b(float f) {
    union { float f; unsigned int i; } v; v.f = f;
    unsigned int x = v.i;
    x += 0x7fffu + ((x >> 16) & 1u);   // round-to-nearest-even
    return (ushort_t)(x >> 16);
}
static __device__ __forceinline__ int clampid(int v) {
    return v < 0 ? 0 : (v >= NN ? NN - 1 : v);   // defensive: no wild addresses
}

// ===========================================================================
// FAST PATH (3-kernel pipeline, needs ws >= 7,091,456 B)
// ===========================================================================

// K1: s0a[n], s1a[n] = features[n] @ wc + bc. One wave per row.
__global__ __launch_bounds__(256) void k_scores(
    const float* __restrict__ feats, const float* __restrict__ wc,
    const float* __restrict__ bc,
    float* __restrict__ s0a, float* __restrict__ s1a)
{
    const int lane = threadIdx.x & 63;
    const int wave = blockIdx.x * 4 + (threadIdx.x >> 6);
    const int nwaves = gridDim.x * 4;

    const float4 wa  = *(const float4*)(wc + lane * 8);
    const float4 wb_ = *(const float4*)(wc + lane * 8 + 4);
    const float w00 = wa.x, w01 = wa.z, w02 = wb_.x, w03 = wb_.z;
    const float w10 = wa.y, w11 = wa.w, w12 = wb_.y, w13 = wb_.w;
    const float bc0 = bc[0], bc1 = bc[1];

    for (int row = wave; row < NN; row += nwaves) {
        const float4 f4 = *(const float4*)(feats + (size_t)row * FD + lane * 4);
        float s0 = f4.x * w00 + f4.y * w01 + f4.z * w02 + f4.w * w03;
        float s1 = f4.x * w10 + f4.y * w11 + f4.z * w12 + f4.w * w13;
        #pragma unroll
        for (int o = 32; o; o >>= 1) {
            s0 += __shfl_xor(s0, o);
            s1 += __shfl_xor(s1, o);
        }
        if (lane == 0) {
            s0a[row] = s0 + bc0;
            s1a[row] = s1 + bc1;
        }
    }
}

// K2: per (32-row batch tile, relation): top-16 select -> gather+mean
// -> GEMM 32x256 @ 256x128 -> relu -> r_buf (bf16). Grid (BB/32, 3).
// LDS 34.9 KB -> 4 blocks/CU. NOTE: no min-waves launch_bounds — R6's
// (256,4) capped VGPR at 64 and caused ~80 MB of scratch spills.
__global__ __launch_bounds__(256) void k_rel(
    const float* __restrict__ feats, const float* __restrict__ s1a,
    const int* __restrict__ nodes,
    const int* __restrict__ n1, const int* __restrict__ n2,
    const int* __restrict__ n3,
    const float* __restrict__ w1, const float* __restrict__ w2,
    const float* __restrict__ w3,
    ushort_t* __restrict__ r_buf)
{
    const int r  = blockIdx.y;
    const int b0 = blockIdx.x * 32;
    const int* nr = (r == 0) ? n1 : (r == 1) ? n2 : n3;
    const float* W = (r == 0) ? w1 : (r == 1) ? w2 : w3;

    __shared__ __align__(16) ushort_t Am[32 * FD];   // mean tile bf16, 16 KB
    __shared__ __align__(16) float Bsm[32 * ED];     // W k-chunk, 16 KB
    __shared__ int   sl[32 * KSEL];                  // 2 KB
    __shared__ float cs1[32];
    int* nb = (int*)Bsm;   // alias: nb dead before Bsm first written

    const int t    = threadIdx.x;
    const int wv   = t >> 6;
    const int lane = t & 63;

    if (t < 32) cs1[t] = s1a[clampid(nodes[b0 + t])];
    #pragma unroll
    for (int jj = 0; jj < 4; ++jj) {
        const int idx = t + 256 * jj;
        nb[idx] = clampid(nr[(size_t)b0 * DD + idx]);
    }
    __syncthreads();

    // prefill sl with valid ids (rank collisions can't leave garbage)
    #pragma unroll
    for (int jj = 0; jj < 2; ++jj) {
        const int idx = t + 256 * jj;          // 0..511
        sl[idx] = nb[(idx >> 4) * DD + (idx & 15)];
    }
    __syncthreads();

    // top-16 by rank (exact jax.lax.top_k stable tie-break)
    {
        const int g = t >> 5;
        const int j = t & 31;
        #pragma unroll
        for (int pass = 0; pass < 4; ++pass) {
            const int row = pass * 8 + g;
            const float d = fabsf(s1a[nb[row * DD + j]] - cs1[row]);
            int rank = 0;
            #pragma unroll
            for (int k = 0; k < 32; ++k) {
                const float dk = __shfl(d, k, 32);
                rank += (dk < d) || (dk == d && k < j);
            }
            if (rank < KSEL) sl[row * KSEL + rank] = nb[row * DD + j];
        }
    }
    __syncthreads();

    // gather + mean, two rows interleaved per iteration (2x loads in flight)
    for (int rr = wv * 8; rr < wv * 8 + 8; rr += 2) {
        float a0 = 0.f, a1 = 0.f, a2 = 0.f, a3 = 0.f;
        float b0v = 0.f, b1v = 0.f, b2v = 0.f, b3v = 0.f;
        #pragma unroll
        for (int k = 0; k < KSEL; ++k) {
            const int s0i = sl[rr * KSEL + k];
            const int s1i = sl[(rr + 1) * KSEL + k];
            const float4 v0 = *(const float4*)(feats + (size_t)s0i * FD + lane * 4);
            const float4 v1 = *(const float4*)(feats + (size_t)s1i * FD + lane * 4);
            a0 += v0.x; a1 += v0.y; a2 += v0.z; a3 += v0.w;
            b0v += v1.x; b1v += v1.y; b2v += v1.z; b3v += v1.w;
        }
        ushort4 oa, ob;
        oa.x = f2b(a0 * 0.0625f);  oa.y = f2b(a1 * 0.0625f);
        oa.z = f2b(a2 * 0.0625f);  oa.w = f2b(a3 * 0.0625f);
        ob.x = f2b(b0v * 0.0625f); ob.y = f2b(b1v * 0.0625f);
        ob.z = f2b(b2v * 0.0625f); ob.w = f2b(b3v * 0.0625f);
        *(ushort4*)(Am + rr * FD + lane * 4)       = oa;
        *(ushort4*)(Am + (rr + 1) * FD + lane * 4) = ob;
    }
    __syncthreads();

    // GEMM 32x256 @ 256x128, BK=32, 4x4 micro-tile, A from bf16 LDS
    const int bt = (t >> 5) * 4;
    const int et = (t & 31) * 4;
    float acc[4][4] = {};

    for (int k0 = 0; k0 < FD; k0 += 32) {
        #pragma unroll
        for (int jj = 0; jj < 4; ++jj) {
            const int c = t + 256 * jj;
            const int row = c >> 5, col4 = (c & 31) * 4;
            *(float4*)(Bsm + row * ED + col4) =
                *(const float4*)(W + (size_t)(k0 + row) * ED + col4);
        }
        __syncthreads();
        #pragma unroll
        for (int kk = 0; kk < 32; kk += 4) {
            ushort4 av[4];
            #pragma unroll
            for (int i = 0; i < 4; ++i)
                av[i] = *(const ushort4*)(Am + (bt + i) * FD + k0 + kk);
            #pragma unroll
            for (int q = 0; q < 4; ++q) {
                const float4 bv = *(const float4*)(Bsm + (kk + q) * ED + et);
                const float a0 = b2f(q == 0 ? av[0].x : q == 1 ? av[0].y : q == 2 ? av[0].z : av[0].w);
                const float a1 = b2f(q == 0 ? av[1].x : q == 1 ? av[1].y : q == 2 ? av[1].z : av[1].w);
                const float a2 = b2f(q == 0 ? av[2].x : q == 1 ? av[2].y : q == 2 ? av[2].z : av[2].w);
                const float a3 = b2f(q == 0 ? av[3].x : q == 1 ? av[3].y : q == 2 ? av[3].z : av[3].w);
                acc[0][0] += a0 * bv.x; acc[0][1] += a0 * bv.y;
                acc[0][2] += a0 * bv.z; acc[0][3] += a0 * bv.w;
                acc[1][0] += a1 * bv.x; acc[1][1] += a1 * bv.y;
                acc[1][2] += a1 * bv.z; acc[1][3] += a1 * bv.w;
                acc[2][0] += a2 * bv.x; acc[2][1] += a2 * bv.y;
                acc[2][2] += a2 * bv.z; acc[2][3] += a2 * bv.w;
                acc[3][0] += a3 * bv.x; acc[3][1] += a3 * bv.y;
                acc[3][2] += a3 * bv.z; acc[3][3] += a3 * bv.w;
            }
        }
        __syncthreads();
    }

    #pragma unroll
    for (int i = 0; i < 4; ++i) {
        ushort4 o;
        const float v0 = acc[i][0], v1 = acc[i][1], v2 = acc[i][2], v3 = acc[i][3];
        o.x = f2b(v0 > 0.f ? v0 : 0.f);
        o.y = f2b(v1 > 0.f ? v1 : 0.f);
        o.z = f2b(v2 > 0.f ? v2 : 0.f);
        o.w = f2b(v3 > 0.f ? v3 : 0.f);
        *(ushort4*)(r_buf + (size_t)(r * BB + b0 + bt + i) * ED + et) = o;
    }
}

// K3: final GEMM 32x640 @ 640x128, A = [feats[nodes] | r_buf], N-split 2.
__global__ __launch_bounds__(256) void k_fin(
    const float* __restrict__ feats, const int* __restrict__ nodes,
    const ushort_t* __restrict__ r_buf, const float* __restrict__ weight,
    const float* __restrict__ s0a, const float* __restrict__ s1a,
    float* __restrict__ out)
{
    const int b0 = blockIdx.x * 32;
    const int e0 = blockIdx.y * 64;
    const int t = threadIdx.x;

    __shared__ __align__(16) unsigned char mem[12800];
    float* Asf = (float*)mem;              // [32*36]  4608 B
    float* Bs2 = (float*)(mem + 4608);     // [32*64]  8192 B
    float* Cs  = (float*)mem;              // [64*36]  epilogue alias
    __shared__ int nid[32];

    if (t < 32) nid[t] = clampid(nodes[b0 + t]);
    __syncthreads();

    if (blockIdx.y == 0 && t < 64) {       // center scores -> out tail
        const int i = t >> 1;
        out[(size_t)ED * BB + (size_t)(b0 + i) * 2 + (t & 1)] =
            (t & 1) ? s1a[nid[i]] : s0a[nid[i]];
    }

    const int arow = t >> 3;
    const int acol = (t & 7) * 4;
    const int bt3 = (t >> 4) * 2;
    const int et3 = (t & 15) * 4;
    float acc[2][4] = {};

    for (int k0 = 0; k0 < FD + 3 * ED; k0 += 32) {
        if (k0 < FD) {
            const float4 v = *(const float4*)(feats + (size_t)nid[arow] * FD + k0 + acol);
            Asf[arow * 36 + acol + 0] = v.x;
            Asf[arow * 36 + acol + 1] = v.y;
            Asf[arow * 36 + acol + 2] = v.z;
            Asf[arow * 36 + acol + 3] = v.w;
        } else {
            const int kr = k0 - FD;
            const ushort4 v = *(const ushort4*)(r_buf +
                (size_t)((kr >> 7) * BB + b0 + arow) * ED + (kr & 127) + acol);
            Asf[arow * 36 + acol + 0] = b2f(v.x);
            Asf[arow * 36 + acol + 1] = b2f(v.y);
            Asf[arow * 36 + acol + 2] = b2f(v.z);
            Asf[arow * 36 + acol + 3] = b2f(v.w);
        }
        #pragma unroll
        for (int jj = 0; jj < 2; ++jj) {
            const int c = t + 256 * jj;        // 0..511
            const int row = c >> 4, col4 = (c & 15) * 4;
            *(float4*)(Bs2 + row * 64 + col4) =
                *(const float4*)(weight + (size_t)(k0 + row) * ED + e0 + col4);
        }
        __syncthreads();
        #pragma unroll
        for (int kk = 0; kk < 32; ++kk) {
            const float a0 = Asf[(bt3 + 0) * 36 + kk];
            const float a1 = Asf[(bt3 + 1) * 36 + kk];
            const float4 bv = *(const float4*)(Bs2 + kk * 64 + et3);
            acc[0][0] += a0 * bv.x; acc[0][1] += a0 * bv.y;
            acc[0][2] += a0 * bv.z; acc[0][3] += a0 * bv.w;
            acc[1][0] += a1 * bv.x; acc[1][1] += a1 * bv.y;
            acc[1][2] += a1 * bv.z; acc[1][3] += a1 * bv.w;
        }
        __syncthreads();
    }

    #pragma unroll
    for (int i = 0; i < 2; ++i)
        #pragma unroll
        for (int j = 0; j < 4; ++j) {
            const float v = acc[i][j];
            Cs[(et3 + j) * 36 + bt3 + i] = v > 0.f ? v : 0.f;
        }
    __syncthreads();
    #pragma unroll
    for (int jj = 0; jj < 2; ++jj) {
        const int c = t + 256 * jj;            // 512 slots: 64 rows x 8 float4
        const int er = c >> 3;
        const int off = (c & 7) * 4;
        *(float4*)(out + (size_t)(e0 + er) * BB + b0 + off) =
            *(const float4*)(Cs + er * 36 + off);
    }
}

// ===========================================================================
// FALLBACK (validated R4 single kernel, zero workspace)
// ===========================================================================
__global__ __launch_bounds__(256) void k_fused(
    const float* __restrict__ feats, const int* __restrict__ nodes,
    const int* __restrict__ n1, const int* __restrict__ n2,
    const int* __restrict__ n3,
    const float* __restrict__ wc, const float* __restrict__ bc,
    const float* __restrict__ w1, const float* __restrict__ w2,
    const float* __restrict__ w3,
    const float* __restrict__ weight, float* __restrict__ out)
{
    __shared__ __align__(16) unsigned char usm[32768];
    __shared__ int      sl[32 * KSEL];
    __shared__ __align__(16) ushort_t Rt[3 * 32 * ED];
    __shared__ int      nid[32];
    __shared__ float    cs1[32];

    int*      nb  = (int*)usm;
    float*    ns1 = (float*)(usm + 4096);
    ushort_t* Am  = (ushort_t*)usm;
    float*    Bsm = (float*)(usm + 16384);
    float*    Asf = (float*)usm;
    float*    Cs  = (float*)usm;

    const int b0   = blockIdx.x * 32;
    const int t    = threadIdx.x;
    const int wv   = t >> 6;
    const int lane = t & 63;

    const float4 wa  = *(const float4*)(wc + lane * 8);
    const float4 wb_ = *(const float4*)(wc + lane * 8 + 4);
    const float w00 = wa.x, w01 = wa.z, w02 = wb_.x, w03 = wb_.z;
    const float w10 = wa.y, w11 = wa.w, w12 = wb_.y, w13 = wb_.w;
    const float bc0 = bc[0], bc1 = bc[1];

    if (t < 32) nid[t] = clampid(nodes[b0 + t]);
    __syncthreads();

    for (int q = 0; q < 8; ++q) {
        const int i = wv * 8 + q;
        const int node = nid[i];
        const float4 f4 = *(const float4*)(feats + (size_t)node * FD + lane * 4);
        float s0 = f4.x * w00 + f4.y * w01 + f4.z * w02 + f4.w * w03;
        float s1 = f4.x * w10 + f4.y * w11 + f4.z * w12 + f4.w * w13;
        #pragma unroll
        for (int o = 32; o; o >>= 1) {
            s0 += __shfl_xor(s0, o);
            s1 += __shfl_xor(s1, o);
        }
        if (lane == 0) {
            cs1[i] = s1 + bc1;
            out[(size_t)ED * BB + (size_t)(b0 + i) * 2]     = s0 + bc0;
            out[(size_t)ED * BB + (size_t)(b0 + i) * 2 + 1] = s1 + bc1;
        }
    }
    __syncthreads();

    const int bt = (t >> 5) * 4;
    const int et = (t & 31) * 4;

    for (int r = 0; r < 3; ++r) {
        const int* nr = (r == 0) ? n1 : (r == 1) ? n2 : n3;
        const float* W = (r == 0) ? w1 : (r == 1) ? w2 : w3;

        #pragma unroll
        for (int jj = 0; jj < 4; ++jj) {
            const int idx = t + 256 * jj;
            nb[idx] = clampid(nr[(size_t)b0 * DD + idx]);
        }
        __syncthreads();

        #pragma unroll
        for (int jj = 0; jj < 2; ++jj) {
            const int idx = t + 256 * jj;
            sl[idx] = nb[(idx >> 4) * DD + (idx & 15)];
        }

        for (int p = wv; p < 32 * DD; p += 4) {
            const int node = nb[p];
            const float4 f4 = *(const float4*)(feats + (size_t)node * FD + lane * 4);
            float s1 = f4.x * w10 + f4.y * w11 + f4.z * w12 + f4.w * w13;
            #pragma unroll
            for (int o = 32; o; o >>= 1) s1 += __shfl_xor(s1, o);
            if (lane == 0) ns1[p] = s1 + bc1;
        }
        __syncthreads();

        {
            const int g = t >> 5;
            const int j = t & 31;
            #pragma unroll
            for (int pass = 0; pass < 4; ++pass) {
                const int row = pass * 8 + g;
                const float d = fabsf(ns1[row * DD + j] - cs1[row]);
                int rank = 0;
                #pragma unroll
                for (int k = 0; k < 32; ++k) {
                    const float dk = __shfl(d, k, 32);
                    rank += (dk < d) || (dk == d && k < j);
                }
                if (rank < KSEL) sl[row * KSEL + rank] = nb[row * DD + j];
            }
        }
        __syncthreads();

        for (int rr = wv * 8; rr < wv * 8 + 8; ++rr) {
            float a0 = 0.f, a1 = 0.f, a2 = 0.f, a3 = 0.f;
            #pragma unroll
            for (int k = 0; k < KSEL; ++k) {
                const int src = sl[rr * KSEL + k];
                const float4 v = *(const float4*)(feats + (size_t)src * FD + lane * 4);
                a0 += v.x; a1 += v.y; a2 += v.z; a3 += v.w;
            }
            ushort4 o;
            o.x = f2b(a0 * 0.0625f); o.y = f2b(a1 * 0.0625f);
            o.z = f2b(a2 * 0.0625f); o.w = f2b(a3 * 0.0625f);
            *(ushort4*)(Am + rr * FD + lane * 4) = o;
        }
        __syncthreads();

        float acc[4][4] = {};
        for (int k0 = 0; k0 < FD; k0 += 32) {
            #pragma unroll
            for (int jj = 0; jj < 4; ++jj) {
                const int c = t + 256 * jj;
                const int row = c >> 5, col4 = (c & 31) * 4;
                *(float4*)(Bsm + row * ED + col4) =
                    *(const float4*)(W + (size_t)(k0 + row) * ED + col4);
            }
            __syncthreads();
            #pragma unroll
            for (int kk = 0; kk < 32; kk += 4) {
                ushort4 av[4];
                #pragma unroll
                for (int i = 0; i < 4; ++i)
                    av[i] = *(const ushort4*)(Am + (bt + i) * FD + k0 + kk);
                #pragma unroll
                for (int q = 0; q < 4; ++q) {
                    const float4 bv = *(const float4*)(Bsm + (kk + q) * ED + et);
                    const float a0 = b2f(q == 0 ? av[0].x : q == 1 ? av[0].y : q == 2 ? av[0].z : av[0].w);
                    const float a1 = b2f(q == 0 ? av[1].x : q == 1 ? av[1].y : q == 2 ? av[1].z : av[1].w);
                    const float a2 = b2f(q == 0 ? av[2].x : q == 1 ? av[2].y : q == 2 ? av[2].z : av[2].w);
                    const float a3 = b2f(q == 0 ? av[3].x : q == 1 ? av[3].y : q == 2 ? av[3].z : av[3].w);
                    acc[0][0] += a0 * bv.x; acc[0][1] += a0 * bv.y;
                    acc[0][2] += a0 * bv.z; acc[0][3] += a0 * bv.w;
                    acc[1][0] += a1 * bv.x; acc[1][1] += a1 * bv.y;
                    acc[1][2] += a1 * bv.z; acc[1][3] += a1 * bv.w;
                    acc[2][0] += a2 * bv.x; acc[2][1] += a2 * bv.y;
                    acc[2][2] += a2 * bv.z; acc[2][3] += a2 * bv.w;
                    acc[3][0] += a3 * bv.x; acc[3][1] += a3 * bv.y;
                    acc[3][2] += a3 * bv.z; acc[3][3] += a3 * bv.w;
                }
            }
            __syncthreads();
        }

        #pragma unroll
        for (int i = 0; i < 4; ++i) {
            ushort4 o;
            const float v0 = acc[i][0], v1 = acc[i][1], v2 = acc[i][2], v3 = acc[i][3];
            o.x = f2b(v0 > 0.f ? v0 : 0.f);
            o.y = f2b(v1 > 0.f ? v1 : 0.f);
            o.z = f2b(v2 > 0.f ? v2 : 0.f);
            o.w = f2b(v3 > 0.f ? v3 : 0.f);
            *(ushort4*)(Rt + (r * 32 + bt + i) * ED + et) = o;
        }
    }

    const int arow = t >> 3;
    const int acol = (t & 7) * 4;
    float acc[4][4] = {};

    for (int k0 = 0; k0 < FD + 3 * ED; k0 += 32) {
        if (k0 < FD) {
            const float4 v = *(const float4*)(feats + (size_t)nid[arow] * FD + k0 + acol);
            Asf[arow * 36 + acol + 0] = v.x;
            Asf[arow * 36 + acol + 1] = v.y;
            Asf[arow * 36 + acol + 2] = v.z;
            Asf[arow * 36 + acol + 3] = v.w;
        } else {
            const int kr = k0 - FD;
            const ushort4 v = *(const ushort4*)(Rt + ((kr >> 7) * 32 + arow) * ED + (kr & 127) + acol);
            Asf[arow * 36 + acol + 0] = b2f(v.x);
            Asf[arow * 36 + acol + 1] = b2f(v.y);
            Asf[arow * 36 + acol + 2] = b2f(v.z);
            Asf[arow * 36 + acol + 3] = b2f(v.w);
        }
        #pragma unroll
        for (int jj = 0; jj < 4; ++jj) {
            const int c = t + 256 * jj;
            const int row = c >> 5, col4 = (c & 31) * 4;
            *(float4*)(Bsm + row * ED + col4) =
                *(const float4*)(weight + (size_t)(k0 + row) * ED + col4);
        }
        __syncthreads();
        #pragma unroll
        for (int kk = 0; kk < 32; ++kk) {
            const float a0 = Asf[(bt + 0) * 36 + kk];
            const float a1 = Asf[(bt + 1) * 36 + kk];
            const float a2 = Asf[(bt + 2) * 36 + kk];
            const float a3 = Asf[(bt + 3) * 36 + kk];
            const float4 bv = *(const float4*)(Bsm + kk * ED + et);
            acc[0][0] += a0 * bv.x; acc[0][1] += a0 * bv.y;
            acc[0][2] += a0 * bv.z; acc[0][3] += a0 * bv.w;
            acc[1][0] += a1 * bv.x; acc[1][1] += a1 * bv.y;
            acc[1][2] += a1 * bv.z; acc[1][3] += a1 * bv.w;
            acc[2][0] += a2 * bv.x; acc[2][1] += a2 * bv.y;
            acc[2][2] += a2 * bv.z; acc[2][3] += a2 * bv.w;
            acc[3][0] += a3 * bv.x; acc[3][1] += a3 * bv.y;
            acc[3][2] += a3 * bv.z; acc[3][3] += a3 * bv.w;
        }
        __syncthreads();
    }

    #pragma unroll
    for (int i = 0; i < 4; ++i)
        #pragma unroll
        for (int j = 0; j < 4; ++j) {
            const float v = acc[i][j];
            Cs[(et + j) * 36 + bt + i] = v > 0.f ? v : 0.f;
        }
    __syncthreads();
    #pragma unroll
    for (int jj = 0; jj < 4; ++jj) {
        const int c = t + 256 * jj;
        const int er = c >> 3;
        const int off = (c & 7) * 4;
        *(float4*)(out + (size_t)er * BB + b0 + off) = *(const float4*)(Cs + er * 36 + off);
    }
}

// ---------------------------------------------------------------------------
// ws layout (fast path): s0a f32[NN]@0, s1a f32[NN]@400000,
// r_buf bf16[3*BB*ED]@800000. Total 7,091,456 B.
// ---------------------------------------------------------------------------
extern "C" void kernel_launch(void* const* d_in, const int* in_sizes, int n_in,
                              void* d_out, int out_size, void* d_ws, size_t ws_size,
                              hipStream_t stream)
{
    const float* feats  = (const float*)d_in[0];
    const int*   nodes  = (const int*)d_in[1];
    const int*   n1     = (const int*)d_in[2];
    const int*   n2     = (const int*)d_in[3];
    const int*   n3     = (const int*)d_in[4];
    const float* wc     = (const float*)d_in[5];
    const float* bc     = (const float*)d_in[6];
    const float* w1     = (const float*)d_in[7];
    const float* w2     = (const float*)d_in[8];
    const float* w3     = (const float*)d_in[9];
    const float* weight = (const float*)d_in[10];
    float* out = (float*)d_out;

    if (ws_size >= 7091456) {
        char* ws = (char*)d_ws;
        float*    s0a   = (float*)(ws + 0);
        float*    s1a   = (float*)(ws + 400000);
        ushort_t* r_buf = (ushort_t*)(ws + 800000);

        k_scores<<<800, 256, 0, stream>>>(feats, wc, bc, s0a, s1a);
        k_rel<<<dim3(BB / 32, 3), 256, 0, stream>>>(
            feats, s1a, nodes, n1, n2, n3, w1, w2, w3, r_buf);
        k_fin<<<dim3(BB / 32, 2), 256, 0, stream>>>(
            feats, nodes, r_buf, weight, s0a, s1a, out);
    } else {
        k_fused<<<BB / 32, 256, 0, stream>>>(feats, nodes, n1, n2, n3,
                                             wc, bc, w1, w2, w3, weight, out);
    }
}

// Round 8
// 272.768 us; speedup vs baseline: 1.1475x; 1.0669x over previous
//
#include <hip/hip_runtime.h>

// Problem constants
#define NN 100000   // nodes
#define FD 256      // feature dim
#define ED 128      // embedding dim
#define BB 8192     // batch
#define DD 32       // neighbors per relation
#define KSEL 16     // top-k

typedef unsigned short ushort_t;
typedef __attribute__((ext_vector_type(8))) short short8;    // 8 bf16 = 4 VGPRs
typedef __attribute__((ext_vector_type(4))) float float4v;   // MFMA C/D

static __device__ __forceinline__ float b2f(ushort_t u) {
    union { float f; unsigned int i; } v; v.i = ((unsigned int)u) << 16; return v.f;
}
static __device__ __forceinline__ ushort_t f2b(float f) {
    union { float f; unsigned int i; } v; v.f = f;
    unsigned int x = v.i;
    x += 0x7fffu + ((x >> 16) & 1u);   // round-to-nearest-even
    return (ushort_t)(x >> 16);
}
static __device__ __forceinline__ int clampid(int v) {
    return v < 0 ? 0 : (v >= NN ? NN - 1 : v);   // defensive: no wild addresses
}

// ===========================================================================
// FAST PATH kernels
// ===========================================================================

// K1: s0a[n], s1a[n] = features[n] @ wc + bc. One wave per row.
__global__ __launch_bounds__(256) void k_scores(
    const float* __restrict__ feats, const float* __restrict__ wc,
    const float* __restrict__ bc,
    float* __restrict__ s0a, float* __restrict__ s1a)
{
    const int lane = threadIdx.x & 63;
    const int wave = blockIdx.x * 4 + (threadIdx.x >> 6);
    const int nwaves = gridDim.x * 4;

    const float4 wa  = *(const float4*)(wc + lane * 8);
    const float4 wb_ = *(const float4*)(wc + lane * 8 + 4);
    const float w00 = wa.x, w01 = wa.z, w02 = wb_.x, w03 = wb_.z;
    const float w10 = wa.y, w11 = wa.w, w12 = wb_.y, w13 = wb_.w;
    const float bc0 = bc[0], bc1 = bc[1];

    for (int row = wave; row < NN; row += nwaves) {
        const float4 f4 = *(const float4*)(feats + (size_t)row * FD + lane * 4);
        float s0 = f4.x * w00 + f4.y * w01 + f4.z * w02 + f4.w * w03;
        float s1 = f4.x * w10 + f4.y * w11 + f4.z * w12 + f4.w * w13;
        #pragma unroll
        for (int o = 32; o; o >>= 1) {
            s0 += __shfl_xor(s0, o);
            s1 += __shfl_xor(s1, o);
        }
        if (lane == 0) {
            s0a[row] = s0 + bc0;
            s1a[row] = s1 + bc1;
        }
    }
}

// K1b: wt[n][k] = bf16(weight[k][n]) — transposed bf16 copy for MFMA B-frags.
__global__ __launch_bounds__(256) void k_wt(
    const float* __restrict__ weight, ushort_t* __restrict__ wt)
{
    const int idx = blockIdx.x * 256 + threadIdx.x;   // < 128*160 = 20480
    const int n  = idx / 160;
    const int k4 = (idx % 160) * 4;
    ushort4 o;
    o.x = f2b(weight[(size_t)(k4 + 0) * ED + n]);
    o.y = f2b(weight[(size_t)(k4 + 1) * ED + n]);
    o.z = f2b(weight[(size_t)(k4 + 2) * ED + n]);
    o.w = f2b(weight[(size_t)(k4 + 3) * ED + n]);
    *(ushort4*)(wt + (size_t)n * 640 + k4) = o;
}

// K2: per (32-row batch tile, relation): top-16 select -> gather+mean
// -> GEMM 32x256 @ 256x128 -> relu -> r_buf (bf16). Grid (BB/32, 3).
// LDS 34.9 KB -> 4 blocks/CU. No min-waves bound (R6: VGPR cap => spills).
__global__ __launch_bounds__(256) void k_rel(
    const float* __restrict__ feats, const float* __restrict__ s1a,
    const int* __restrict__ nodes,
    const int* __restrict__ n1, const int* __restrict__ n2,
    const int* __restrict__ n3,
    const float* __restrict__ w1, const float* __restrict__ w2,
    const float* __restrict__ w3,
    ushort_t* __restrict__ r_buf)
{
    const int r  = blockIdx.y;
    const int b0 = blockIdx.x * 32;
    const int* nr = (r == 0) ? n1 : (r == 1) ? n2 : n3;
    const float* W = (r == 0) ? w1 : (r == 1) ? w2 : w3;

    __shared__ __align__(16) ushort_t Am[32 * FD];   // mean tile bf16, 16 KB
    __shared__ __align__(16) float Bsm[32 * ED];     // W k-chunk, 16 KB
    __shared__ int   sl[32 * KSEL];                  // 2 KB
    __shared__ float cs1[32];
    int* nb = (int*)Bsm;   // alias: nb dead before Bsm first written

    const int t    = threadIdx.x;
    const int wv   = t >> 6;
    const int lane = t & 63;

    if (t < 32) cs1[t] = s1a[clampid(nodes[b0 + t])];
    #pragma unroll
    for (int jj = 0; jj < 4; ++jj) {
        const int idx = t + 256 * jj;
        nb[idx] = clampid(nr[(size_t)b0 * DD + idx]);
    }
    __syncthreads();

    // prefill sl with valid ids (rank collisions can't leave garbage)
    #pragma unroll
    for (int jj = 0; jj < 2; ++jj) {
        const int idx = t + 256 * jj;          // 0..511
        sl[idx] = nb[(idx >> 4) * DD + (idx & 15)];
    }
    __syncthreads();

    // top-16 by rank (exact jax.lax.top_k stable tie-break)
    {
        const int g = t >> 5;
        const int j = t & 31;
        #pragma unroll
        for (int pass = 0; pass < 4; ++pass) {
            const int row = pass * 8 + g;
            const float d = fabsf(s1a[nb[row * DD + j]] - cs1[row]);
            int rank = 0;
            #pragma unroll
            for (int k = 0; k < 32; ++k) {
                const float dk = __shfl(d, k, 32);
                rank += (dk < d) || (dk == d && k < j);
            }
            if (rank < KSEL) sl[row * KSEL + rank] = nb[row * DD + j];
        }
    }
    __syncthreads();

    // gather + mean, two rows interleaved per iteration
    for (int rr = wv * 8; rr < wv * 8 + 8; rr += 2) {
        float a0 = 0.f, a1 = 0.f, a2 = 0.f, a3 = 0.f;
        float b0v = 0.f, b1v = 0.f, b2v = 0.f, b3v = 0.f;
        #pragma unroll
        for (int k = 0; k < KSEL; ++k) {
            const int s0i = sl[rr * KSEL + k];
            const int s1i = sl[(rr + 1) * KSEL + k];
            const float4 v0 = *(const float4*)(feats + (size_t)s0i * FD + lane * 4);
            const float4 v1 = *(const float4*)(feats + (size_t)s1i * FD + lane * 4);
            a0 += v0.x; a1 += v0.y; a2 += v0.z; a3 += v0.w;
            b0v += v1.x; b1v += v1.y; b2v += v1.z; b3v += v1.w;
        }
        ushort4 oa, ob;
        oa.x = f2b(a0 * 0.0625f);  oa.y = f2b(a1 * 0.0625f);
        oa.z = f2b(a2 * 0.0625f);  oa.w = f2b(a3 * 0.0625f);
        ob.x = f2b(b0v * 0.0625f); ob.y = f2b(b1v * 0.0625f);
        ob.z = f2b(b2v * 0.0625f); ob.w = f2b(b3v * 0.0625f);
        *(ushort4*)(Am + rr * FD + lane * 4)       = oa;
        *(ushort4*)(Am + (rr + 1) * FD + lane * 4) = ob;
    }
    __syncthreads();

    // GEMM 32x256 @ 256x128, BK=32, 4x4 micro-tile, A from bf16 LDS
    const int bt = (t >> 5) * 4;
    const int et = (t & 31) * 4;
    float acc[4][4] = {};

    for (int k0 = 0; k0 < FD; k0 += 32) {
        #pragma unroll
        for (int jj = 0; jj < 4; ++jj) {
            const int c = t + 256 * jj;
            const int row = c >> 5, col4 = (c & 31) * 4;
            *(float4*)(Bsm + row * ED + col4) =
                *(const float4*)(W + (size_t)(k0 + row) * ED + col4);
        }
        __syncthreads();
        #pragma unroll
        for (int kk = 0; kk < 32; kk += 4) {
            ushort4 av[4];
            #pragma unroll
            for (int i = 0; i < 4; ++i)
                av[i] = *(const ushort4*)(Am + (bt + i) * FD + k0 + kk);
            #pragma unroll
            for (int q = 0; q < 4; ++q) {
                const float4 bv = *(const float4*)(Bsm + (kk + q) * ED + et);
                const float a0 = b2f(q == 0 ? av[0].x : q == 1 ? av[0].y : q == 2 ? av[0].z : av[0].w);
                const float a1 = b2f(q == 0 ? av[1].x : q == 1 ? av[1].y : q == 2 ? av[1].z : av[1].w);
                const float a2 = b2f(q == 0 ? av[2].x : q == 1 ? av[2].y : q == 2 ? av[2].z : av[2].w);
                const float a3 = b2f(q == 0 ? av[3].x : q == 1 ? av[3].y : q == 2 ? av[3].z : av[3].w);
                acc[0][0] += a0 * bv.x; acc[0][1] += a0 * bv.y;
                acc[0][2] += a0 * bv.z; acc[0][3] += a0 * bv.w;
                acc[1][0] += a1 * bv.x; acc[1][1] += a1 * bv.y;
                acc[1][2] += a1 * bv.z; acc[1][3] += a1 * bv.w;
                acc[2][0] += a2 * bv.x; acc[2][1] += a2 * bv.y;
                acc[2][2] += a2 * bv.z; acc[2][3] += a2 * bv.w;
                acc[3][0] += a3 * bv.x; acc[3][1] += a3 * bv.y;
                acc[3][2] += a3 * bv.z; acc[3][3] += a3 * bv.w;
            }
        }
        __syncthreads();
    }

    #pragma unroll
    for (int i = 0; i < 4; ++i) {
        ushort4 o;
        const float v0 = acc[i][0], v1 = acc[i][1], v2 = acc[i][2], v3 = acc[i][3];
        o.x = f2b(v0 > 0.f ? v0 : 0.f);
        o.y = f2b(v1 > 0.f ? v1 : 0.f);
        o.z = f2b(v2 > 0.f ? v2 : 0.f);
        o.w = f2b(v3 > 0.f ? v3 : 0.f);
        *(ushort4*)(r_buf + (size_t)(r * BB + b0 + bt + i) * ED + et) = o;
    }
}

// K3 (MFMA): final GEMM 32x640 @ 640x128 via v_mfma_f32_16x16x32_bf16.
// Grid BB/32 = 256. A (32x640 bf16) staged once in LDS (stride 648: frag
// b128 reads 2-way-conflict-free). B-frags read directly from wt (global,
// 16B/lane within 64B row segments, L2-resident). No K-loop barriers.
// Layouts (HW-verified m89/m120): A[m=lane&15][k=quad*8+j],
// B[k][n=lane&15], D col=lane&15 row=quad*4+reg.
__global__ __launch_bounds__(256) void k_fin_mfma(
    const float* __restrict__ feats, const int* __restrict__ nodes,
    const ushort_t* __restrict__ r_buf, const ushort_t* __restrict__ wt,
    const float* __restrict__ s0a, const float* __restrict__ s1a,
    float* __restrict__ out)
{
    const int b0 = blockIdx.x * 32;
    const int t  = threadIdx.x;

    __shared__ __align__(16) ushort_t At[32 * 648];   // 41,472 B
    float* Cs = (float*)At;                            // epilogue alias
    __shared__ int nid[32];

    if (t < 32) nid[t] = clampid(nodes[b0 + t]);
    __syncthreads();

    if (t < 64) {                       // center scores -> out tail
        const int i = t >> 1;
        out[(size_t)ED * BB + (size_t)(b0 + i) * 2 + (t & 1)] =
            (t & 1) ? s1a[nid[i]] : s0a[nid[i]];
    }

    // stage A: self-feats (k<256), fp32 -> bf16
    #pragma unroll
    for (int i = 0; i < 8; ++i) {
        const int idx = t + 256 * i;          // 0..2047 = 32 rows x 64 float4
        const int row = idx >> 6, c4 = idx & 63;
        const float4 v = *(const float4*)(feats + (size_t)nid[row] * FD + c4 * 4);
        ushort4 o;
        o.x = f2b(v.x); o.y = f2b(v.y); o.z = f2b(v.z); o.w = f2b(v.w);
        *(ushort4*)(At + row * 648 + c4 * 4) = o;
    }
    // stage A: relation outputs (k in 256..640), already bf16
    #pragma unroll
    for (int i = 0; i < 12; ++i) {
        const int idx = t + 256 * i;          // 0..3071 = 32 rows x 96 ushort4
        const int row = idx / 96;
        const int c   = (idx % 96) * 4;       // 0..380
        const ushort4 v = *(const ushort4*)(r_buf +
            (size_t)((c >> 7) * BB + b0 + row) * ED + (c & 127));
        *(ushort4*)(At + row * 648 + FD + c) = v;
    }
    __syncthreads();

    const int wv   = t >> 6;
    const int lane = t & 63;
    const int quad = lane >> 4;
    const int ln   = lane & 15;
    const int mt   = wv & 1;              // m-tile (0/1): rows mt*16..+15
    const int n0   = (wv >> 1) * 64;      // 4 n-tiles of 16 cols

    const ushort_t* Arow  = At + (mt * 16 + ln) * 648 + quad * 8;
    const ushort_t* Bbase = wt + (size_t)(n0 + ln) * 640 + quad * 8;

    float4v acc[4] = {};
    for (int k0 = 0; k0 < 640; k0 += 32) {
        const short8 a = *(const short8*)(Arow + k0);
        #pragma unroll
        for (int nt = 0; nt < 4; ++nt) {
            const short8 b = *(const short8*)(Bbase + nt * 16 * 640 + k0);
            acc[nt] = __builtin_amdgcn_mfma_f32_16x16x32_bf16(a, b, acc[nt], 0, 0, 0);
        }
    }
    __syncthreads();   // all waves done reading At before Cs alias reuse

    #pragma unroll
    for (int nt = 0; nt < 4; ++nt)
        #pragma unroll
        for (int reg = 0; reg < 4; ++reg) {
            const float v = acc[nt][reg];
            const int n = n0 + nt * 16 + ln;
            const int m = mt * 16 + quad * 4 + reg;
            Cs[n * 36 + m] = v > 0.f ? v : 0.f;
        }
    __syncthreads();
    #pragma unroll
    for (int j = 0; j < 4; ++j) {
        const int idx = t + 256 * j;          // 1024 slots: 128 rows x 8 float4
        const int er = idx >> 3, off = (idx & 7) * 4;
        *(float4*)(out + (size_t)er * BB + b0 + off) = *(const float4*)(Cs + er * 36 + off);
    }
}

// K3 (fp32 fallback tier): final GEMM, N-split 2. Proven in R5-R7.
__global__ __launch_bounds__(256) void k_fin(
    const float* __restrict__ feats, const int* __restrict__ nodes,
    const ushort_t* __restrict__ r_buf, const float* __restrict__ weight,
    const float* __restrict__ s0a, const float* __restrict__ s1a,
    float* __restrict__ out)
{
    const int b0 = blockIdx.x * 32;
    const int e0 = blockIdx.y * 64;
    const int t = threadIdx.x;

    __shared__ __align__(16) unsigned char mem[12800];
    float* Asf = (float*)mem;
    float* Bs2 = (float*)(mem + 4608);
    float* Cs  = (float*)mem;
    __shared__ int nid[32];

    if (t < 32) nid[t] = clampid(nodes[b0 + t]);
    __syncthreads();

    if (blockIdx.y == 0 && t < 64) {
        const int i = t >> 1;
        out[(size_t)ED * BB + (size_t)(b0 + i) * 2 + (t & 1)] =
            (t & 1) ? s1a[nid[i]] : s0a[nid[i]];
    }

    const int arow = t >> 3;
    const int acol = (t & 7) * 4;
    const int bt3 = (t >> 4) * 2;
    const int et3 = (t & 15) * 4;
    float acc[2][4] = {};

    for (int k0 = 0; k0 < FD + 3 * ED; k0 += 32) {
        if (k0 < FD) {
            const float4 v = *(const float4*)(feats + (size_t)nid[arow] * FD + k0 + acol);
            Asf[arow * 36 + acol + 0] = v.x;
            Asf[arow * 36 + acol + 1] = v.y;
            Asf[arow * 36 + acol + 2] = v.z;
            Asf[arow * 36 + acol + 3] = v.w;
        } else {
            const int kr = k0 - FD;
            const ushort4 v = *(const ushort4*)(r_buf +
                (size_t)((kr >> 7) * BB + b0 + arow) * ED + (kr & 127) + acol);
            Asf[arow * 36 + acol + 0] = b2f(v.x);
            Asf[arow * 36 + acol + 1] = b2f(v.y);
            Asf[arow * 36 + acol + 2] = b2f(v.z);
            Asf[arow * 36 + acol + 3] = b2f(v.w);
        }
        #pragma unroll
        for (int jj = 0; jj < 2; ++jj) {
            const int c = t + 256 * jj;
            const int row = c >> 4, col4 = (c & 15) * 4;
            *(float4*)(Bs2 + row * 64 + col4) =
                *(const float4*)(weight + (size_t)(k0 + row) * ED + e0 + col4);
        }
        __syncthreads();
        #pragma unroll
        for (int kk = 0; kk < 32; ++kk) {
            const float a0 = Asf[(bt3 + 0) * 36 + kk];
            const float a1 = Asf[(bt3 + 1) * 36 + kk];
            const float4 bv = *(const float4*)(Bs2 + kk * 64 + et3);
            acc[0][0] += a0 * bv.x; acc[0][1] += a0 * bv.y;
            acc[0][2] += a0 * bv.z; acc[0][3] += a0 * bv.w;
            acc[1][0] += a1 * bv.x; acc[1][1] += a1 * bv.y;
            acc[1][2] += a1 * bv.z; acc[1][3] += a1 * bv.w;
        }
        __syncthreads();
    }

    #pragma unroll
    for (int i = 0; i < 2; ++i)
        #pragma unroll
        for (int j = 0; j < 4; ++j) {
            const float v = acc[i][j];
            Cs[(et3 + j) * 36 + bt3 + i] = v > 0.f ? v : 0.f;
        }
    __syncthreads();
    #pragma unroll
    for (int jj = 0; jj < 2; ++jj) {
        const int c = t + 256 * jj;
        const int er = c >> 3;
        const int off = (c & 7) * 4;
        *(float4*)(out + (size_t)(e0 + er) * BB + b0 + off) =
            *(const float4*)(Cs + er * 36 + off);
    }
}

// ===========================================================================
// FALLBACK (validated R4 single kernel, zero workspace)
// ===========================================================================
__global__ __launch_bounds__(256) void k_fused(
    const float* __restrict__ feats, const int* __restrict__ nodes,
    const int* __restrict__ n1, const int* __restrict__ n2,
    const int* __restrict__ n3,
    const float* __restrict__ wc, const float* __restrict__ bc,
    const float* __restrict__ w1, const float* __restrict__ w2,
    const float* __restrict__ w3,
    const float* __restrict__ weight, float* __restrict__ out)
{
    __shared__ __align__(16) unsigned char usm[32768];
    __shared__ int      sl[32 * KSEL];
    __shared__ __align__(16) ushort_t Rt[3 * 32 * ED];
    __shared__ int      nid[32];
    __shared__ float    cs1[32];

    int*      nb  = (int*)usm;
    float*    ns1 = (float*)(usm + 4096);
    ushort_t* Am  = (ushort_t*)usm;
    float*    Bsm = (float*)(usm + 16384);
    float*    Asf = (float*)usm;
    float*    Cs  = (float*)usm;

    const int b0   = blockIdx.x * 32;
    const int t    = threadIdx.x;
    const int wv   = t >> 6;
    const int lane = t & 63;

    const float4 wa  = *(const float4*)(wc + lane * 8);
    const float4 wb_ = *(const float4*)(wc + lane * 8 + 4);
    const float w00 = wa.x, w01 = wa.z, w02 = wb_.x, w03 = wb_.z;
    const float w10 = wa.y, w11 = wa.w, w12 = wb_.y, w13 = wb_.w;
    const float bc0 = bc[0], bc1 = bc[1];

    if (t < 32) nid[t] = clampid(nodes[b0 + t]);
    __syncthreads();

    for (int q = 0; q < 8; ++q) {
        const int i = wv * 8 + q;
        const int node = nid[i];
        const float4 f4 = *(const float4*)(feats + (size_t)node * FD + lane * 4);
        float s0 = f4.x * w00 + f4.y * w01 + f4.z * w02 + f4.w * w03;
        float s1 = f4.x * w10 + f4.y * w11 + f4.z * w12 + f4.w * w13;
        #pragma unroll
        for (int o = 32; o; o >>= 1) {
            s0 += __shfl_xor(s0, o);
            s1 += __shfl_xor(s1, o);
        }
        if (lane == 0) {
            cs1[i] = s1 + bc1;
            out[(size_t)ED * BB + (size_t)(b0 + i) * 2]     = s0 + bc0;
            out[(size_t)ED * BB + (size_t)(b0 + i) * 2 + 1] = s1 + bc1;
        }
    }
    __syncthreads();

    const int bt = (t >> 5) * 4;
    const int et = (t & 31) * 4;

    for (int r = 0; r < 3; ++r) {
        const int* nr = (r == 0) ? n1 : (r == 1) ? n2 : n3;
        const float* W = (r == 0) ? w1 : (r == 1) ? w2 : w3;

        #pragma unroll
        for (int jj = 0; jj < 4; ++jj) {
            const int idx = t + 256 * jj;
            nb[idx] = clampid(nr[(size_t)b0 * DD + idx]);
        }
        __syncthreads();

        #pragma unroll
        for (int jj = 0; jj < 2; ++jj) {
            const int idx = t + 256 * jj;
            sl[idx] = nb[(idx >> 4) * DD + (idx & 15)];
        }

        for (int p = wv; p < 32 * DD; p += 4) {
            const int node = nb[p];
            const float4 f4 = *(const float4*)(feats + (size_t)node * FD + lane * 4);
            float s1 = f4.x * w10 + f4.y * w11 + f4.z * w12 + f4.w * w13;
            #pragma unroll
            for (int o = 32; o; o >>= 1) s1 += __shfl_xor(s1, o);
            if (lane == 0) ns1[p] = s1 + bc1;
        }
        __syncthreads();

        {
            const int g = t >> 5;
            const int j = t & 31;
            #pragma unroll
            for (int pass = 0; pass < 4; ++pass) {
                const int row = pass * 8 + g;
                const float d = fabsf(ns1[row * DD + j] - cs1[row]);
                int rank = 0;
                #pragma unroll
                for (int k = 0; k < 32; ++k) {
                    const float dk = __shfl(d, k, 32);
                    rank += (dk < d) || (dk == d && k < j);
                }
                if (rank < KSEL) sl[row * KSEL + rank] = nb[row * DD + j];
            }
        }
        __syncthreads();

        for (int rr = wv * 8; rr < wv * 8 + 8; ++rr) {
            float a0 = 0.f, a1 = 0.f, a2 = 0.f, a3 = 0.f;
            #pragma unroll
            for (int k = 0; k < KSEL; ++k) {
                const int src = sl[rr * KSEL + k];
                const float4 v = *(const float4*)(feats + (size_t)src * FD + lane * 4);
                a0 += v.x; a1 += v.y; a2 += v.z; a3 += v.w;
            }
            ushort4 o;
            o.x = f2b(a0 * 0.0625f); o.y = f2b(a1 * 0.0625f);
            o.z = f2b(a2 * 0.0625f); o.w = f2b(a3 * 0.0625f);
            *(ushort4*)(Am + rr * FD + lane * 4) = o;
        }
        __syncthreads();

        float acc[4][4] = {};
        for (int k0 = 0; k0 < FD; k0 += 32) {
            #pragma unroll
            for (int jj = 0; jj < 4; ++jj) {
                const int c = t + 256 * jj;
                const int row = c >> 5, col4 = (c & 31) * 4;
                *(float4*)(Bsm + row * ED + col4) =
                    *(const float4*)(W + (size_t)(k0 + row) * ED + col4);
            }
            __syncthreads();
            #pragma unroll
            for (int kk = 0; kk < 32; kk += 4) {
                ushort4 av[4];
                #pragma unroll
                for (int i = 0; i < 4; ++i)
                    av[i] = *(const ushort4*)(Am + (bt + i) * FD + k0 + kk);
                #pragma unroll
                for (int q = 0; q < 4; ++q) {
                    const float4 bv = *(const float4*)(Bsm + (kk + q) * ED + et);
                    const float a0 = b2f(q == 0 ? av[0].x : q == 1 ? av[0].y : q == 2 ? av[0].z : av[0].w);
                    const float a1 = b2f(q == 0 ? av[1].x : q == 1 ? av[1].y : q == 2 ? av[1].z : av[1].w);
                    const float a2 = b2f(q == 0 ? av[2].x : q == 1 ? av[2].y : q == 2 ? av[2].z : av[2].w);
                    const float a3 = b2f(q == 0 ? av[3].x : q == 1 ? av[3].y : q == 2 ? av[3].z : av[3].w);
                    acc[0][0] += a0 * bv.x; acc[0][1] += a0 * bv.y;
                    acc[0][2] += a0 * bv.z; acc[0][3] += a0 * bv.w;
                    acc[1][0] += a1 * bv.x; acc[1][1] += a1 * bv.y;
                    acc[1][2] += a1 * bv.z; acc[1][3] += a1 * bv.w;
                    acc[2][0] += a2 * bv.x; acc[2][1] += a2 * bv.y;
                    acc[2][2] += a2 * bv.z; acc[2][3] += a2 * bv.w;
                    acc[3][0] += a3 * bv.x; acc[3][1] += a3 * bv.y;
                    acc[3][2] += a3 * bv.z; acc[3][3] += a3 * bv.w;
                }
            }
            __syncthreads();
        }

        #pragma unroll
        for (int i = 0; i < 4; ++i) {
            ushort4 o;
            const float v0 = acc[i][0], v1 = acc[i][1], v2 = acc[i][2], v3 = acc[i][3];
            o.x = f2b(v0 > 0.f ? v0 : 0.f);
            o.y = f2b(v1 > 0.f ? v1 : 0.f);
            o.z = f2b(v2 > 0.f ? v2 : 0.f);
            o.w = f2b(v3 > 0.f ? v3 : 0.f);
            *(ushort4*)(Rt + (r * 32 + bt + i) * ED + et) = o;
        }
    }

    const int arow = t >> 3;
    const int acol = (t & 7) * 4;
    float acc[4][4] = {};

    for (int k0 = 0; k0 < FD + 3 * ED; k0 += 32) {
        if (k0 < FD) {
            const float4 v = *(const float4*)(feats + (size_t)nid[arow] * FD + k0 + acol);
            Asf[arow * 36 + acol + 0] = v.x;
            Asf[arow * 36 + acol + 1] = v.y;
            Asf[arow * 36 + acol + 2] = v.z;
            Asf[arow * 36 + acol + 3] = v.w;
        } else {
            const int kr = k0 - FD;
            const ushort4 v = *(const ushort4*)(Rt + ((kr >> 7) * 32 + arow) * ED + (kr & 127) + acol);
            Asf[arow * 36 + acol + 0] = b2f(v.x);
            Asf[arow * 36 + acol + 1] = b2f(v.y);
            Asf[arow * 36 + acol + 2] = b2f(v.z);
            Asf[arow * 36 + acol + 3] = b2f(v.w);
        }
        #pragma unroll
        for (int jj = 0; jj < 4; ++jj) {
            const int c = t + 256 * jj;
            const int row = c >> 5, col4 = (c & 31) * 4;
            *(float4*)(Bsm + row * ED + col4) =
                *(const float4*)(weight + (size_t)(k0 + row) * ED + col4);
        }
        __syncthreads();
        #pragma unroll
        for (int kk = 0; kk < 32; ++kk) {
            const float a0 = Asf[(bt + 0) * 36 + kk];
            const float a1 = Asf[(bt + 1) * 36 + kk];
            const float a2 = Asf[(bt + 2) * 36 + kk];
            const float a3 = Asf[(bt + 3) * 36 + kk];
            const float4 bv = *(const float4*)(Bsm + kk * ED + et);
            acc[0][0] += a0 * bv.x; acc[0][1] += a0 * bv.y;
            acc[0][2] += a0 * bv.z; acc[0][3] += a0 * bv.w;
            acc[1][0] += a1 * bv.x; acc[1][1] += a1 * bv.y;
            acc[1][2] += a1 * bv.z; acc[1][3] += a1 * bv.w;
            acc[2][0] += a2 * bv.x; acc[2][1] += a2 * bv.y;
            acc[2][2] += a2 * bv.z; acc[2][3] += a2 * bv.w;
            acc[3][0] += a3 * bv.x; acc[3][1] += a3 * bv.y;
            acc[3][2] += a3 * bv.z; acc[3][3] += a3 * bv.w;
        }
        __syncthreads();
    }

    #pragma unroll
    for (int i = 0; i < 4; ++i)
        #pragma unroll
        for (int j = 0; j < 4; ++j) {
            const float v = acc[i][j];
            Cs[(et + j) * 36 + bt + i] = v > 0.f ? v : 0.f;
        }
    __syncthreads();
    #pragma unroll
    for (int jj = 0; jj < 4; ++jj) {
        const int c = t + 256 * jj;
        const int er = c >> 3;
        const int off = (c & 7) * 4;
        *(float4*)(out + (size_t)er * BB + b0 + off) = *(const float4*)(Cs + er * 36 + off);
    }
}

// ---------------------------------------------------------------------------
// ws layout: s0a f32[NN]@0, s1a f32[NN]@400000, r_buf bf16[3*BB*ED]@800000,
// wt bf16[128*640]@7091456. Total 7,255,296 B.
// ---------------------------------------------------------------------------
extern "C" void kernel_launch(void* const* d_in, const int* in_sizes, int n_in,
                              void* d_out, int out_size, void* d_ws, size_t ws_size,
                              hipStream_t stream)
{
    const float* feats  = (const float*)d_in[0];
    const int*   nodes  = (const int*)d_in[1];
    const int*   n1     = (const int*)d_in[2];
    const int*   n2     = (const int*)d_in[3];
    const int*   n3     = (const int*)d_in[4];
    const float* wc     = (const float*)d_in[5];
    const float* bc     = (const float*)d_in[6];
    const float* w1     = (const float*)d_in[7];
    const float* w2     = (const float*)d_in[8];
    const float* w3     = (const float*)d_in[9];
    const float* weight = (const float*)d_in[10];
    float* out = (float*)d_out;

    if (ws_size >= 7091456) {
        char* ws = (char*)d_ws;
        float*    s0a   = (float*)(ws + 0);
        float*    s1a   = (float*)(ws + 400000);
        ushort_t* r_buf = (ushort_t*)(ws + 800000);
        ushort_t* wt    = (ushort_t*)(ws + 7091456);

        k_scores<<<800, 256, 0, stream>>>(feats, wc, bc, s0a, s1a);
        if (ws_size >= 7255296)
            k_wt<<<80, 256, 0, stream>>>(weight, wt);
        k_rel<<<dim3(BB / 32, 3), 256, 0, stream>>>(
            feats, s1a, nodes, n1, n2, n3, w1, w2, w3, r_buf);
        if (ws_size >= 7255296)
            k_fin_mfma<<<BB / 32, 256, 0, stream>>>(
                feats, nodes, r_buf, wt, s0a, s1a, out);
        else
            k_fin<<<dim3(BB / 32, 2), 256, 0, stream>>>(
                feats, nodes, r_buf, weight, s0a, s1a, out);
    } else {
        k_fused<<<BB / 32, 256, 0, stream>>>(feats, nodes, n1, n2, n3,
                                             wc, bc, w1, w2, w3, weight, out);
    }
}